// Round 6
// baseline (735.373 us; speedup 1.0000x reference)
//
#include <hip/hip_runtime.h>
#include <hip/hip_bf16.h>
#include <math.h>

#define B_ 8
#define S_ 4096
#define D_ 512
#define H_ 8
#define DK_ 64
#define DFF_ 1024
#define SPLIT_ 16
#define KVSZ_ 4160   /* 64*64 + 64 (KV matrix + ksum) */
#define EPS_ 1e-6f
#define LN_EPS_ 1e-5f

typedef __attribute__((ext_vector_type(8))) short bf16x8;
typedef __attribute__((ext_vector_type(4))) float f32x4;

static __device__ __forceinline__ float b2f(unsigned short u) {
  unsigned int x = ((unsigned int)u) << 16;
  return __builtin_bit_cast(float, x);
}
static __device__ __forceinline__ unsigned short f2b(float f) {
  unsigned int u = __builtin_bit_cast(unsigned int, f);
  u += 0x7FFFu + ((u >> 16) & 1u);   // round-to-nearest-even
  return (unsigned short)(u >> 16);
}

// ---------------------------------------------------------------------------
// fp32 -> bf16 convert (RNE), 8 elems/thread. n8 = n/8.
// ---------------------------------------------------------------------------
__global__ __launch_bounds__(256) void cvt_f32_bf16(
    const float* __restrict__ in, unsigned short* __restrict__ out, int n8)
{
  const int i = blockIdx.x * 256 + threadIdx.x;
  if (i >= n8) return;
  f32x4 a = ((const f32x4*)in)[i * 2];
  f32x4 b = ((const f32x4*)in)[i * 2 + 1];
  bf16x8 o;
  #pragma unroll
  for (int e = 0; e < 4; ++e) { o[e] = (short)f2b(a[e]); o[e + 4] = (short)f2b(b[e]); }
  ((bf16x8*)out)[i] = o;
}

// ---------------------------------------------------------------------------
// All 6 weight matrices -> bf16, packed contiguously at wb. Also packs qkv
// biases into bqkv[1536]. Total vec8 groups = 262144 -> 1024 blocks.
// ---------------------------------------------------------------------------
__global__ __launch_bounds__(256) void cvt_weights(
    const float* __restrict__ wq, const float* __restrict__ wk,
    const float* __restrict__ wv, const float* __restrict__ wo,
    const float* __restrict__ w1, const float* __restrict__ w2,
    const float* __restrict__ bq, const float* __restrict__ bk,
    const float* __restrict__ bv,
    unsigned short* __restrict__ wb, float* __restrict__ bqkv)
{
  const int i = blockIdx.x * 256 + threadIdx.x;   // vec8 id, 262144 total
  const float* src; int rel;
  if (i < 65536)       { src = (i < 32768)  ? wq : wk; rel = i & 32767; }
  else if (i < 131072) { src = (i < 98304)  ? wv : wo; rel = (i - 65536) & 32767; }
  else                 { src = (i < 196608) ? w1 : w2; rel = (i - 131072) & 65535; }
  f32x4 a = ((const f32x4*)src)[rel * 2];
  f32x4 b = ((const f32x4*)src)[rel * 2 + 1];
  bf16x8 o;
  #pragma unroll
  for (int e = 0; e < 4; ++e) { o[e] = (short)f2b(a[e]); o[e + 4] = (short)f2b(b[e]); }
  ((bf16x8*)wb)[i] = o;
  if (i < 1536) bqkv[i] = (i < 512) ? bq[i] : (i < 1024 ? bk[i - 512] : bv[i - 1024]);
}

// ---------------------------------------------------------------------------
// 8-phase 256x256 GEMM (m201 template port): C[M,N] = A@W^T + bias.
// 512 thr = 8 waves (2M x 4N); per-wave C = 128x64 = 8x4 16x16 frags.
// BK=64; 2 LDS slots (one K-tile each: 32KB A + 32KB B); 2 K-tiles/iter.
// LDS row order REMAPPED so each 16KB staging half-unit == the stripe set
// read in one phase (race-freedom):
//   A lds row = mhalf*128 + mw*64 + rr   (unit A_h = phys rows h*128..+127)
//   B lds row = nhalf*128 + nw*32 + rr
// Bank swizzle (G4-proven): byte col ^= (ldsrow&7)<<4, applied on READ and
// inverted on the STAGING SOURCE address (linear gload_lds dest, rule #21).
// Phases (per K-tile): q0{rd A_mh0,B_nh0 | mfma(m0,n0)} q1{rd B_nh1 | stage A0
// | mfma(m0,n1)} q2{rd A_mh1 | stage B0 | mfma(m1,n0)} q3{stage B1,A1 |
// vmcnt(8) | mfma(m1,n1)}; each phase = reads/stages -> barrier -> lgkmcnt(0)
// -> setprio(1) MFMA setprio(0) -> barrier.  vmcnt(8) (= 8 newest loads of
// the just-staged tile still in flight) guarantees the PREVIOUS prefetched
// tile fully landed before the next 4 phases read it. Never drains in-loop.
// EPI: 0=bias; 1=bias+gelu^2(erf); 2=fused-QKV slot routing (stride 512).
// ---------------------------------------------------------------------------
template<int EPI>
__global__ __launch_bounds__(512, 2) void gemm8p(
    const unsigned short* __restrict__ A,
    const unsigned short* __restrict__ Wm,
    const float* __restrict__ bias,
    unsigned short* __restrict__ C,
    int M, int N, int K, int ntx)
{
  __shared__ unsigned short sA[2][16384];   // 64 KB
  __shared__ unsigned short sB[2][16384];   // 64 KB
  const int t = threadIdx.x;
  const int wave = t >> 6, lane = t & 63;
  const int logical = ((int)blockIdx.x & 7) * ((int)gridDim.x >> 3) + ((int)blockIdx.x >> 3);
  const int row0 = (logical / ntx) << 8;
  const int col0 = (logical % ntx) << 8;

  const int mw = wave >> 2;          // 0..1  (M wave group)
  const int nw = wave & 3;           // 0..3  (N wave group)
  const int fr = lane & 15;
  const int g16 = (lane >> 4) << 4;  // 16B chunk byte offset within K-row

  // --- staging source pointers: for linear dest D, the content is the global
  // chunk whose swizzled+remapped position is D.  [mat][half][j]
  const unsigned short* gsrc[2][2][2];
  #pragma unroll
  for (int h = 0; h < 2; ++h)
    #pragma unroll
    for (int j = 0; j < 2; ++j) {
      const int D    = h * 16384 + j * 8192 + t * 16;   // byte in 32KB tile
      const int prow = D >> 7;                          // phys lds row
      const int cole = ((D & 127) ^ ((prow & 7) << 4)) >> 1;  // elem col
      const int ar = ((prow >> 6) & 1) * 128 + (prow >> 7) * 64 + (prow & 63);
      const int br = ((prow & 127) >> 5) * 64 + (prow >> 7) * 32 + (prow & 31);
      gsrc[0][h][j] = A  + (size_t)(row0 + ar) * K + cole;
      gsrc[1][h][j] = Wm + (size_t)(col0 + br) * K + cole;
    }

  // gload_lds dest = wave-uniform base (HW adds lane*16B)
#define STG(mat, slot, h, j, kt)                                               \
  __builtin_amdgcn_global_load_lds(                                            \
      (const __attribute__((address_space(1))) void*)(gsrc[mat][h][j] + (size_t)(kt) * 64), \
      (__attribute__((address_space(3))) void*)(((mat) ? &sB[slot][0] : &sA[slot][0]) + (h) * 8192 + (j) * 4096 + wave * 512), \
      16, 0, 0)

  f32x4 acc[8][4] = {};
  bf16x8 af[4][2], bf[2][2][2];

#define RD_A(slot, mhalf)                                                      \
  { _Pragma("unroll") for (int mfi = 0; mfi < 4; ++mfi)                        \
      _Pragma("unroll") for (int ks = 0; ks < 2; ++ks) {                       \
        const int lr = (mhalf) * 128 + mw * 64 + mfi * 16 + fr;                \
        const int cb = (ks * 64 + g16) ^ ((lr & 7) << 4);                      \
        af[mfi][ks] = *(const bf16x8*)((const char*)&sA[slot][0] + lr * 128 + cb); } }
#define RD_B(slot, nhalf)                                                      \
  { _Pragma("unroll") for (int nfi = 0; nfi < 2; ++nfi)                        \
      _Pragma("unroll") for (int ks = 0; ks < 2; ++ks) {                       \
        const int lr = (nhalf) * 128 + nw * 32 + nfi * 16 + fr;                \
        const int cb = (ks * 64 + g16) ^ ((lr & 7) << 4);                      \
        bf[nhalf][nfi][ks] = *(const bf16x8*)((const char*)&sB[slot][0] + lr * 128 + cb); } }
#define MMQ(mhalf, nhalf)                                                      \
  { __builtin_amdgcn_s_setprio(1);                                             \
    _Pragma("unroll") for (int mfi = 0; mfi < 4; ++mfi)                        \
      _Pragma("unroll") for (int nfi = 0; nfi < 2; ++nfi)                      \
        _Pragma("unroll") for (int ks = 0; ks < 2; ++ks)                       \
          acc[(mhalf)*4+mfi][(nhalf)*2+nfi] = __builtin_amdgcn_mfma_f32_16x16x32_bf16( \
              af[mfi][ks], bf[nhalf][nfi][ks], acc[(mhalf)*4+mfi][(nhalf)*2+nfi], 0, 0, 0); \
    __builtin_amdgcn_s_setprio(0); }
#define BAR() __builtin_amdgcn_s_barrier()
#define LGKM0() { asm volatile("s_waitcnt lgkmcnt(0)" ::: "memory"); __builtin_amdgcn_sched_barrier(0); }
#define VMC(n)  asm volatile("s_waitcnt vmcnt(" #n ")" ::: "memory")

  // ---- prologue: tile0 -> slot0 (8 oldest), tile1 -> slot1 (8 newest) ----
  STG(0,0,0,0,0); STG(0,0,0,1,0); STG(0,0,1,0,0); STG(0,0,1,1,0);
  STG(1,0,0,0,0); STG(1,0,0,1,0); STG(1,0,1,0,0); STG(1,0,1,1,0);
  STG(0,1,0,0,1); STG(0,1,0,1,1); STG(0,1,1,0,1); STG(0,1,1,1,1);
  STG(1,1,0,0,1); STG(1,1,0,1,1); STG(1,1,1,0,1); STG(1,1,1,1,1);
  VMC(8);          // tile0 landed; tile1's 8 still in flight
  BAR();

  const int nt2 = K >> 7;     // iterations, 2 K-tiles each
  for (int i = 0; i < nt2; ++i) {
    const bool st = (i + 1 < nt2);
    const int k2 = 2 * i + 2, k3 = 2 * i + 3;
    // ---------- first half: compute tile 2i (slot0); stage tile 2i+2 ----------
    RD_A(0, 0); RD_B(0, 0);
    BAR(); LGKM0(); MMQ(0, 0); BAR();                       // q0
    RD_B(0, 1);
    if (st) { STG(0,0,0,0,k2); STG(0,0,0,1,k2); }           // A0 (read q0)
    BAR(); LGKM0(); MMQ(0, 1); BAR();                       // q1
    RD_A(0, 1);
    if (st) { STG(1,0,0,0,k2); STG(1,0,0,1,k2); }           // B0 (read q0)
    BAR(); LGKM0(); MMQ(1, 0); BAR();                       // q2
    if (st) { STG(1,0,1,0,k2); STG(1,0,1,1,k2);             // B1 (read q1)
              STG(0,0,1,0,k2); STG(0,0,1,1,k2);             // A1 (read q2)
              VMC(8); }                                     // tile 2i+1 landed
    else      VMC(0);
    BAR(); MMQ(1, 1); BAR();                                // q3
    // ---------- second half: compute tile 2i+1 (slot1); stage tile 2i+3 -------
    RD_A(1, 0); RD_B(1, 0);
    BAR(); LGKM0(); MMQ(0, 0); BAR();                       // q4
    RD_B(1, 1);
    if (st) { STG(0,1,0,0,k3); STG(0,1,0,1,k3); }
    BAR(); LGKM0(); MMQ(0, 1); BAR();                       // q5
    RD_A(1, 1);
    if (st) { STG(1,1,0,0,k3); STG(1,1,0,1,k3); }
    BAR(); LGKM0(); MMQ(1, 0); BAR();                       // q6
    if (st) { STG(1,1,1,0,k3); STG(1,1,1,1,k3);
              STG(0,1,1,0,k3); STG(0,1,1,1,k3);
              VMC(8); }                                     // tile 2i+2 landed
    BAR(); MMQ(1, 1); BAR();                                // q7
  }
#undef STG
#undef RD_A
#undef RD_B
#undef MMQ
#undef BAR
#undef LGKM0
#undef VMC

  // ---- epilogue: C/D layout col=lane&15, row=(lane>>4)*4+reg (m89) ----
  const int crow0 = row0 + mw * 128 + ((lane >> 4) << 2);
  const int ccol0 = col0 + nw * 64 + fr;
  unsigned short* Cb = C;
  int cstr = N;
  if (EPI == 2) { Cb = C + (size_t)(col0 >> 9) * M * 512; cstr = 512; }
  #pragma unroll
  for (int nf = 0; nf < 4; ++nf) {
    const int col = ccol0 + nf * 16;
    const float bv = bias[col];
    const int lcol = (EPI == 2) ? (col & 511) : col;
    #pragma unroll
    for (int mf = 0; mf < 8; ++mf) {
      #pragma unroll
      for (int r = 0; r < 4; ++r) {
        float v = acc[mf][nf][r] + bv;
        if (EPI == 1) {
          float g = 0.5f * v * (1.0f + erff(v * 0.70710678118654752f));
          v = g * g;
        }
        Cb[(size_t)(crow0 + mf * 16 + r) * cstr + lcol] = f2b(v);
      }
    }
  }
}

// ---------------------------------------------------------------------------
// Depthwise causal conv over seq (KS=3, left zero-pad), weight [DK,3] fp32.
// ELUP1: apply elu(x)+1 == (x>0 ? x+1 : exp(x)).  One thread per 8 channels.
// ---------------------------------------------------------------------------
template<bool ELUP1>
__global__ __launch_bounds__(256) void dwconv(
    const unsigned short* __restrict__ in,
    const float* __restrict__ cw,
    const float* __restrict__ cb,
    unsigned short* __restrict__ out)
{
  const int vid = blockIdx.x * 256 + threadIdx.x; // vec8 index, B*S*64 total
  const int d8 = vid & 63;
  const int bs = vid >> 6;        // b*S + s
  const int s  = bs & (S_ - 1);
  const int d0 = d8 << 3;
  const int dk0 = d0 & 63;        // channel within head_dim

  float acc[8], wf[3][8];
  #pragma unroll
  for (int i = 0; i < 8; ++i) acc[i] = cb[dk0 + i];
  #pragma unroll
  for (int j = 0; j < 3; ++j)
    #pragma unroll
    for (int i = 0; i < 8; ++i) wf[j][i] = cw[(dk0 + i) * 3 + j];

  const size_t base = (size_t)bs * D_ + d0;
  #pragma unroll
  for (int j = 0; j < 3; ++j) {
    const int sr = s - 2 + j;
    if (sr >= 0) {
      bf16x8 xv = *(const bf16x8*)(in + base - (size_t)(2 - j) * D_);
      #pragma unroll
      for (int i = 0; i < 8; ++i) acc[i] += wf[j][i] * b2f((unsigned short)xv[i]);
    }
  }
  bf16x8 ov;
  #pragma unroll
  for (int i = 0; i < 8; ++i) {
    float v = acc[i];
    if (ELUP1) v = (v > 0.0f) ? (v + 1.0f) : expf(v);
    ov[i] = (short)f2b(v);
  }
  *(bf16x8*)(out + base) = ov;
}

// ---------------------------------------------------------------------------
// KV partial reduction: per (b,h,split) block accumulate KV[64][64] and
// ksum[64] over a 256-row S-range. fp32 partials to ws.
// ---------------------------------------------------------------------------
__global__ __launch_bounds__(256) void kv_partial(
    const unsigned short* __restrict__ kf,
    const unsigned short* __restrict__ vf,
    float* __restrict__ part)
{
  __shared__ unsigned short kc[16 * 64];
  __shared__ float vc[16 * 64];
  const int t = threadIdx.x;
  const int bh = blockIdx.x;
  const int b = bh >> 3, h = bh & 7;
  const int s0 = blockIdx.y * (S_ / SPLIT_);
  const int d = t >> 2;
  const int e0 = (t & 3) << 4;
  const int lr = (t & 127) >> 3;   // 0..15 row in chunk
  const int lc = (t & 7) << 3;     // 0..56 col

  float acc[16] = {};
  float ksum = 0.0f;

  for (int chunk = 0; chunk < S_ / SPLIT_; chunk += 16) {
    const size_t g = ((size_t)(b * S_ + s0 + chunk + lr)) * D_ + h * 64 + lc;
    if (t < 128) {
      *(bf16x8*)(kc + lr * 64 + lc) = *(const bf16x8*)(kf + g);
    } else {
      bf16x8 vv = *(const bf16x8*)(vf + g);
      #pragma unroll
      for (int i = 0; i < 8; ++i) vc[lr * 64 + lc + i] = b2f((unsigned short)vv[i]);
    }
    __syncthreads();
    #pragma unroll 4
    for (int ss = 0; ss < 16; ++ss) {
      const float kd = b2f(kc[ss * 64 + d]);
      ksum += kd;
      #pragma unroll
      for (int j = 0; j < 16; ++j) acc[j] += kd * vc[ss * 64 + e0 + j];
    }
    __syncthreads();
  }
  float* dst = part + ((size_t)bh * SPLIT_ + blockIdx.y) * KVSZ_;
  #pragma unroll
  for (int j = 0; j < 16; ++j) dst[d * 64 + e0 + j] = acc[j];
  if ((t & 3) == 0) dst[4096 + d] = ksum;
}

__global__ __launch_bounds__(256) void kv_finalize(
    const float* __restrict__ part, float* __restrict__ fin)
{
  const int bh = blockIdx.x;
  for (int idx = threadIdx.x; idx < KVSZ_; idx += 256) {
    float s = 0.0f;
    for (int p = 0; p < SPLIT_; ++p) s += part[((size_t)bh * SPLIT_ + p) * KVSZ_ + idx];
    if (idx >= 4096) s += EPS_;   // K.sum + EPS (per-component)
    fin[(size_t)bh * KVSZ_ + idx] = s;
  }
}

// ---------------------------------------------------------------------------
// attn[b,s,h,:] = (q[b,s,h,:] @ KV[b,h]) / (q . (ksum+eps))
// ---------------------------------------------------------------------------
__global__ __launch_bounds__(256) void attn_out(
    const unsigned short* __restrict__ qf,
    const float* __restrict__ fin,
    unsigned short* __restrict__ attn)
{
  __shared__ float kv[64 * 64];
  __shared__ float ks[64];
  const int t = threadIdx.x;
  const int bh = blockIdx.x, b = bh >> 3, h = bh & 7;
  const int s = blockIdx.y * 64 + (t >> 2);
  const int e0 = (t & 3) << 4;

  const float* src = fin + (size_t)bh * KVSZ_;
  for (int i = t; i < 4096; i += 256) kv[i] = src[i];
  if (t < 64) ks[t] = src[4096 + t];
  __syncthreads();

  const unsigned short* qrow = qf + ((size_t)(b * S_ + s)) * D_ + h * 64;
  float q[64];
  #pragma unroll
  for (int i = 0; i < 8; ++i) {
    bf16x8 qv = *(const bf16x8*)(qrow + i * 8);
    #pragma unroll
    for (int k = 0; k < 8; ++k) q[i * 8 + k] = b2f((unsigned short)qv[k]);
  }
  float zden = 0.0f;
  #pragma unroll
  for (int dd = 0; dd < 64; ++dd) zden += q[dd] * ks[dd];
  const float z = 1.0f / zden;

  float acc[16] = {};
  for (int dd = 0; dd < 64; ++dd) {
    const float qd = q[dd];
    #pragma unroll
    for (int j = 0; j < 16; ++j) acc[j] += qd * kv[dd * 64 + e0 + j];
  }
  unsigned short* orow = attn + ((size_t)(b * S_ + s)) * D_ + h * 64 + e0;
  bf16x8 o0, o1;
  #pragma unroll
  for (int j = 0; j < 8; ++j) { o0[j] = (short)f2b(acc[j] * z); o1[j] = (short)f2b(acc[8 + j] * z); }
  *(bf16x8*)(orow) = o0;
  *(bf16x8*)(orow + 8) = o1;
}

// ---------------------------------------------------------------------------
// out = LayerNorm(xa + xb) * g + b ; one wave per 512-elem row, fp32 math.
// AF32: xa is fp32 (else bf16).  OF32: out is fp32 (else bf16). xb is bf16.
// ---------------------------------------------------------------------------
template<bool AF32, bool OF32>
__global__ __launch_bounds__(256) void ln_add(
    const void* __restrict__ xa_,
    const unsigned short* __restrict__ xb,
    const float* __restrict__ gg,
    const float* __restrict__ bb,
    void* __restrict__ out_)
{
  const int t = threadIdx.x, lane = t & 63, w = t >> 6;
  const size_t row = (size_t)blockIdx.x * 4 + w;
  const size_t base = row * D_ + lane * 8;

  float v[8];
  if (AF32) {
    const float* xa = (const float*)xa_;
    f32x4 a0 = *(const f32x4*)(xa + base);
    f32x4 a1 = *(const f32x4*)(xa + base + 4);
    #pragma unroll
    for (int i = 0; i < 4; ++i) { v[i] = a0[i]; v[i + 4] = a1[i]; }
  } else {
    bf16x8 a = *(const bf16x8*)((const unsigned short*)xa_ + base);
    #pragma unroll
    for (int i = 0; i < 8; ++i) v[i] = b2f((unsigned short)a[i]);
  }
  bf16x8 c = *(const bf16x8*)(xb + base);
  float sum = 0.0f;
  #pragma unroll
  for (int i = 0; i < 8; ++i) { v[i] += b2f((unsigned short)c[i]); sum += v[i]; }
  #pragma unroll
  for (int off = 1; off < 64; off <<= 1) sum += __shfl_xor(sum, off, 64);
  const float mean = sum * (1.0f / 512.0f);
  float sq = 0.0f;
  #pragma unroll
  for (int i = 0; i < 8; ++i) { const float dd = v[i] - mean; sq += dd * dd; }
  #pragma unroll
  for (int off = 1; off < 64; off <<= 1) sq += __shfl_xor(sq, off, 64);
  const float rstd = rsqrtf(sq * (1.0f / 512.0f) + LN_EPS_);

  if (OF32) {
    float* out = (float*)out_;
    f32x4 o0, o1;
    #pragma unroll
    for (int i = 0; i < 4; ++i) {
      o0[i] = (v[i] - mean) * rstd * gg[lane * 8 + i] + bb[lane * 8 + i];
      o1[i] = (v[i + 4] - mean) * rstd * gg[lane * 8 + i + 4] + bb[lane * 8 + i + 4];
    }
    *(f32x4*)(out + base) = o0;
    *(f32x4*)(out + base + 4) = o1;
  } else {
    unsigned short* out = (unsigned short*)out_;
    bf16x8 o;
    #pragma unroll
    for (int i = 0; i < 8; ++i)
      o[i] = (short)f2b((v[i] - mean) * rstd * gg[lane * 8 + i] + bb[lane * 8 + i]);
    *(bf16x8*)(out + base) = o;
  }
}

// ---------------------------------------------------------------------------
extern "C" void kernel_launch(void* const* d_in, const int* in_sizes, int n_in,
                              void* d_out, int out_size, void* d_ws, size_t ws_size,
                              hipStream_t stream) {
  const float* x    = (const float*)d_in[0];
  const float* wq   = (const float*)d_in[1];
  const float* bq   = (const float*)d_in[2];
  const float* wk   = (const float*)d_in[3];
  const float* bk   = (const float*)d_in[4];
  const float* wv   = (const float*)d_in[5];
  const float* bv   = (const float*)d_in[6];
  const float* wo   = (const float*)d_in[7];
  const float* bo   = (const float*)d_in[8];
  const float* qcw  = (const float*)d_in[9];
  const float* qcb  = (const float*)d_in[10];
  const float* kcw  = (const float*)d_in[11];
  const float* kcb  = (const float*)d_in[12];
  const float* vcw  = (const float*)d_in[13];
  const float* vcb  = (const float*)d_in[14];
  const float* w1   = (const float*)d_in[15];
  const float* b1   = (const float*)d_in[16];
  const float* w2   = (const float*)d_in[17];
  const float* b2   = (const float*)d_in[18];
  const float* ln1g = (const float*)d_in[19];
  const float* ln1b = (const float*)d_in[20];
  const float* ln2g = (const float*)d_in[21];
  const float* ln2b = (const float*)d_in[22];

  const size_t E = (size_t)B_ * S_ * D_;   // 16,777,216 elems per slot
  unsigned short* s0 = (unsigned short*)d_ws;
  unsigned short* s1 = s0 + E;
  unsigned short* s2 = s0 + 2 * E;
  unsigned short* s3 = s0 + 3 * E;
  float* part = (float*)s2;                              // 17.0 MB (fits slot 2)
  float* fin  = part + (size_t)64 * SPLIT_ * KVSZ_;      // +1.06 MB

  // bf16 weights stashed in d_out (dead until the final LN overwrites it);
  // packed contiguously: [wq|wk|wv|wo|w1|w2], then packed qkv bias (fp32).
  unsigned short* wb = (unsigned short*)d_out;
  unsigned short* wqkv_b = wb;               // [1536][512]
  unsigned short* wo_b   = wb + 786432;
  unsigned short* w1_b   = wb + 1048576;
  unsigned short* w2_b   = wb + 1572864;
  float* bqkv = (float*)(wb + 2097152);      // 1536 floats

  const int M = B_ * S_;                     // 32768

  // converts: x -> s3 (bf16), all weights+bias pack in ONE kernel
  cvt_f32_bf16<<<(int)(E / 8 / 256), 256, 0, stream>>>(x, s3, (int)(E / 8));
  cvt_weights<<<1024, 256, 0, stream>>>(wq, wk, wv, wo, w1, w2, bq, bk, bv, wb, bqkv);

  // fused q,k,v projection: N=1536 stacked; outputs routed to s0/s1/s2
  gemm8p<2><<<768, 512, 0, stream>>>(s3, wqkv_b, bqkv, s0, M, 1536, D_, 6);
  // depthwise convs (+elu+1 for q,k); qf overwrites the bf16-x slot (dead now)
  dwconv<true ><<<M * 64 / 256, 256, 0, stream>>>(s0, qcw, qcb, s3);  // qf -> s3
  dwconv<true ><<<M * 64 / 256, 256, 0, stream>>>(s1, kcw, kcb, s0);  // kf -> s0
  dwconv<false><<<M * 64 / 256, 256, 0, stream>>>(s2, vcw, vcb, s1);  // vf -> s1
  // KV / ksum reduction
  kv_partial<<<dim3(B_ * H_, SPLIT_), 256, 0, stream>>>(s0, s1, part);
  kv_finalize<<<B_ * H_, 256, 0, stream>>>(part, fin);
  // attention output
  attn_out<<<dim3(B_ * H_, S_ / 64), 256, 0, stream>>>(s3, fin, s0);  // attn -> s0
  // output projection
  gemm8p<0><<<256, 512, 0, stream>>>(s0, wo_b, bo, s1, M, D_, D_, 2);   // o -> s1
  // x1 = LN(x + o)  (x fp32, o bf16 -> x1 bf16)
  ln_add<true, false><<<M / 4, 256, 0, stream>>>(x, s1, ln1g, ln1b, s3);
  // FFN
  gemm8p<1><<<512, 512, 0, stream>>>(s3, w1_b, b1, s0, M, DFF_, D_, 4);   // h -> s0..s1
  gemm8p<0><<<256, 512, 0, stream>>>(s0, w2_b, b2, s2, M, D_, DFF_, 2);   // ffn -> s2
  // out = LN(x1 + ffn) -> fp32 d_out (weight scratch overwritten, now dead)
  ln_add<false, true><<<M / 4, 256, 0, stream>>>(s3, s2, ln2g, ln2b, d_out);
}

// Round 7
// 630.374 us; speedup vs baseline: 1.1666x; 1.1666x over previous
//
#include <hip/hip_runtime.h>
#include <hip/hip_bf16.h>
#include <math.h>

#define B_ 8
#define S_ 4096
#define D_ 512
#define H_ 8
#define DK_ 64
#define DFF_ 1024
#define SPLIT_ 16
#define KVSZ_ 4160   /* 64*64 + 64 (KV matrix + ksum) */
#define EPS_ 1e-6f
#define LN_EPS_ 1e-5f

typedef __attribute__((ext_vector_type(8))) short bf16x8;
typedef __attribute__((ext_vector_type(4))) float f32x4;

static __device__ __forceinline__ float b2f(unsigned short u) {
  unsigned int x = ((unsigned int)u) << 16;
  return __builtin_bit_cast(float, x);
}
static __device__ __forceinline__ unsigned short f2b(float f) {
  unsigned int u = __builtin_bit_cast(unsigned int, f);
  u += 0x7FFFu + ((u >> 16) & 1u);   // round-to-nearest-even
  return (unsigned short)(u >> 16);
}
static __device__ __forceinline__ float elu1(float v) {
  return (v > 0.0f) ? (v + 1.0f) : expf(v);
}

// ---------------------------------------------------------------------------
// fp32 -> bf16 convert (RNE), 8 elems/thread. n8 = n/8.
// ---------------------------------------------------------------------------
__global__ __launch_bounds__(256) void cvt_f32_bf16(
    const float* __restrict__ in, unsigned short* __restrict__ out, int n8)
{
  const int i = blockIdx.x * 256 + threadIdx.x;
  if (i >= n8) return;
  f32x4 a = ((const f32x4*)in)[i * 2];
  f32x4 b = ((const f32x4*)in)[i * 2 + 1];
  bf16x8 o;
  #pragma unroll
  for (int e = 0; e < 4; ++e) { o[e] = (short)f2b(a[e]); o[e + 4] = (short)f2b(b[e]); }
  ((bf16x8*)out)[i] = o;
}

// ---------------------------------------------------------------------------
// All 6 weight matrices -> bf16, packed contiguously at wb. Also packs qkv
// biases into bqkv[1536]. Total vec8 groups = 262144 -> 1024 blocks.
// ---------------------------------------------------------------------------
__global__ __launch_bounds__(256) void cvt_weights(
    const float* __restrict__ wq, const float* __restrict__ wk,
    const float* __restrict__ wv, const float* __restrict__ wo,
    const float* __restrict__ w1, const float* __restrict__ w2,
    const float* __restrict__ bq, const float* __restrict__ bk,
    const float* __restrict__ bv,
    unsigned short* __restrict__ wb, float* __restrict__ bqkv)
{
  const int i = blockIdx.x * 256 + threadIdx.x;   // vec8 id, 262144 total
  const float* src; int rel;
  if (i < 65536)       { src = (i < 32768)  ? wq : wk; rel = i & 32767; }
  else if (i < 131072) { src = (i < 98304)  ? wv : wo; rel = (i - 65536) & 32767; }
  else                 { src = (i < 196608) ? w1 : w2; rel = (i - 131072) & 65535; }
  f32x4 a = ((const f32x4*)src)[rel * 2];
  f32x4 b = ((const f32x4*)src)[rel * 2 + 1];
  bf16x8 o;
  #pragma unroll
  for (int e = 0; e < 4; ++e) { o[e] = (short)f2b(a[e]); o[e + 4] = (short)f2b(b[e]); }
  ((bf16x8*)wb)[i] = o;
  if (i < 1536) bqkv[i] = (i < 512) ? bq[i] : (i < 1024 ? bk[i - 512] : bv[i - 1024]);
}

// ---------------------------------------------------------------------------
// GEMM: C[M,N] = A[M,K] @ W[N,K]^T + bias, bf16 A/W, fp32 bias, bf16 out.
// 128x256 tile, BK=32, 4 waves (each 64x128 = 4x8 16x16 frags).
// 3-deep pipeline with LATE counted wait: per iter
//   barrier -> STAGE(kt+2) [18 outstanding] -> vmcnt(12) [tile kt landed,
//   kt+1 & kt+2 in flight => 2-iteration prefetch lead] -> ds_read/MFMA.
// Tail: vmcnt(6) at nt-2, vmcnt(0) at nt-1. Compiler handles lgkmcnt.
// 1-D grid + bijective XCD swizzle (nwg % 8 == 0).
// EPI: 0 = bias; 1 = bias + gelu(x)^2 (exact erf); 2 = fused-QKV dst routing.
// ---------------------------------------------------------------------------
template<int EPI>
__global__ __launch_bounds__(256, 2) void gemm_bt(
    const unsigned short* __restrict__ A,
    const unsigned short* __restrict__ W,
    const float* __restrict__ bias,
    unsigned short* __restrict__ C,
    int M, int N, int K, int ntx)
{
  __shared__ unsigned short sA[3 * 128 * 32];   // 24 KB
  __shared__ unsigned short sB[3 * 256 * 32];   // 48 KB
  const int t = threadIdx.x;
  const int wave = t >> 6;
  const int lane = t & 63;
  const int bid = blockIdx.x;
  const int logical = (bid & 7) * ((int)gridDim.x >> 3) + (bid >> 3);
  const int row0 = (logical / ntx) << 7;   // 128-row tile
  const int col0 = (logical % ntx) << 8;   // 256-col tile

  f32x4 acc[4][8] = {};

  // staging geometry: per wave, 64 lanes x 16B cover 512 elems (16 rows x 32).
  const int srow = (wave << 4) + (lane >> 2);   // 0..63
  const int scol = (lane & 3) << 3;             // 0,8,16,24
  const unsigned short* ga = A + (size_t)(row0 + srow) * K + scol;
  const unsigned short* gb = W + (size_t)(col0 + srow) * K + scol;
  const int ldsoff = (wave << 9);               // wave-uniform elem offset

  const int wm = (wave >> 1) << 6;    // wave A-row quadrant (0/64)
  const int wn = (wave & 1) << 7;     // wave C-col half (0/128)
  const int fr = lane & 15;           // fragment row (A-M / B-N) index
  const int fk = (lane >> 4) << 3;    // fragment K offset (8 contiguous)

  // 6 global_load_lds per thread per stage (2 for A-tile, 4 for B-tile).
  #define STAGE(bufsel, kt)                                                     \
    {                                                                           \
      _Pragma("unroll")                                                         \
      for (int i = 0; i < 2; ++i)                                               \
        __builtin_amdgcn_global_load_lds(                                       \
            (const __attribute__((address_space(1))) void*)(ga + (size_t)(i * 64) * K + (kt)), \
            (__attribute__((address_space(3))) void*)(sA + (bufsel) * 4096 + i * 2048 + ldsoff), \
            16, 0, 0);                                                          \
      _Pragma("unroll")                                                         \
      for (int i = 0; i < 4; ++i)                                               \
        __builtin_amdgcn_global_load_lds(                                       \
            (const __attribute__((address_space(1))) void*)(gb + (size_t)(i * 64) * K + (kt)), \
            (__attribute__((address_space(3))) void*)(sB + (bufsel) * 8192 + i * 2048 + ldsoff), \
            16, 0, 0);                                                          \
    }

  const int nt = K >> 5;
  STAGE(0, 0);
  STAGE(1, 32);

  int cur = 0, nxt = 2;
  for (int kt = 0; kt < nt; ++kt) {
    __builtin_amdgcn_s_barrier();          // prev iter's reads done; safe to overwrite
    asm volatile("" ::: "memory");
    if (kt + 2 < nt) {
      STAGE(nxt, (kt + 2) * 32);           // 18 outstanding after this
      nxt = (nxt == 2) ? 0 : nxt + 1;
      asm volatile("s_waitcnt vmcnt(12)" ::: "memory");   // tile kt landed
    } else if (kt + 1 < nt) {
      asm volatile("s_waitcnt vmcnt(6)" ::: "memory");
    } else {
      asm volatile("s_waitcnt vmcnt(0)" ::: "memory");
    }

    const unsigned short* pA = sA + cur * 4096;
    const unsigned short* pB = sB + cur * 8192;
    bf16x8 af[4], bfv[8];
    #pragma unroll
    for (int i = 0; i < 4; ++i)
      af[i] = *(const bf16x8*)(pA + (wm + i * 16 + fr) * 32 + fk);
    #pragma unroll
    for (int j = 0; j < 8; ++j)
      bfv[j] = *(const bf16x8*)(pB + (wn + j * 16 + fr) * 32 + fk);
    #pragma unroll
    for (int i = 0; i < 4; ++i)
      #pragma unroll
      for (int j = 0; j < 8; ++j)
        acc[i][j] = __builtin_amdgcn_mfma_f32_16x16x32_bf16(af[i], bfv[j], acc[i][j], 0, 0, 0);

    cur = (cur == 2) ? 0 : cur + 1;
  }
  #undef STAGE

  // C/D layout (m89-verified): col = lane&15, row = (lane>>4)*4 + reg
  const int crow0 = row0 + wm + ((lane >> 4) << 2);
  const int ccol0 = col0 + wn + fr;
  unsigned short* Cb = C;
  if (EPI == 2) Cb = C + (size_t)(col0 >> 9) * M * 512;   // q/k/v slot
  const int cstride = (EPI == 2) ? 512 : N;
  #pragma unroll
  for (int j = 0; j < 8; ++j) {
    const int col = ccol0 + j * 16;
    const float bv = bias[col];
    const int lcol = (EPI == 2) ? (col & 511) : col;
    #pragma unroll
    for (int i = 0; i < 4; ++i) {
      #pragma unroll
      for (int r = 0; r < 4; ++r) {
        float v = acc[i][j][r] + bv;
        if (EPI == 1) {
          float g = 0.5f * v * (1.0f + erff(v * 0.70710678118654752f));
          v = g * g;
        }
        Cb[(size_t)(crow0 + i * 16 + r) * cstride + lcol] = f2b(v);
      }
    }
  }
}

// ---------------------------------------------------------------------------
// KV partial reduction with FUSED depthwise conv (+elu+1 for k).
// Inputs are RAW k_proj / v_proj. Staging threads (t<128: k rows, t>=128: v
// rows) read rows s, s-1, s-2 from global (L2-hot) and write the CONV'D value
// (float) into LDS; main loop is unchanged. Per (b,h,split): KV[64][64]+ksum.
// ---------------------------------------------------------------------------
__global__ __launch_bounds__(256) void kv_partial(
    const unsigned short* __restrict__ kp,
    const unsigned short* __restrict__ vp,
    const float* __restrict__ kcw, const float* __restrict__ kcb,
    const float* __restrict__ vcw, const float* __restrict__ vcb,
    float* __restrict__ part)
{
  __shared__ float kc[16 * 64];
  __shared__ float vc[16 * 64];
  const int t = threadIdx.x;
  const int bh = blockIdx.x;
  const int b = bh >> 3, h = bh & 7;
  const int s0 = blockIdx.y * (S_ / SPLIT_);
  const int d = t >> 2;
  const int e0 = (t & 3) << 4;
  const int lr = (t & 127) >> 3;   // 0..15 row in chunk
  const int lc = (t & 7) << 3;     // 0..56 col
  const bool isv = t >= 128;

  // conv weights for my 8 channels
  const float* cw = isv ? vcw : kcw;
  const float* cb = isv ? vcb : kcb;
  float w0[8], w1[8], w2[8], wb[8];
  #pragma unroll
  for (int i = 0; i < 8; ++i) {
    w0[i] = cw[(lc + i) * 3 + 0];
    w1[i] = cw[(lc + i) * 3 + 1];
    w2[i] = cw[(lc + i) * 3 + 2];
    wb[i] = cb[lc + i];
  }
  const unsigned short* src = isv ? vp : kp;
  float* dstc = isv ? vc : kc;

  float acc[16] = {};
  float ksum = 0.0f;

  for (int chunk = 0; chunk < S_ / SPLIT_; chunk += 16) {
    const int s = s0 + chunk + lr;
    const size_t g = ((size_t)(b * S_ + s)) * D_ + h * 64 + lc;
    bf16x8 r0 = *(const bf16x8*)(src + g);
    bf16x8 r1 = {}, r2 = {};
    if (s >= 1) r1 = *(const bf16x8*)(src + g - D_);
    if (s >= 2) r2 = *(const bf16x8*)(src + g - 2 * D_);
    #pragma unroll
    for (int i = 0; i < 8; ++i) {
      float v = w2[i] * b2f((unsigned short)r0[i])
              + w1[i] * b2f((unsigned short)r1[i])
              + w0[i] * b2f((unsigned short)r2[i]) + wb[i];
      if (!isv) v = elu1(v);
      dstc[lr * 64 + lc + i] = v;
    }
    __syncthreads();
    #pragma unroll 4
    for (int ss = 0; ss < 16; ++ss) {
      const float kd = kc[ss * 64 + d];
      ksum += kd;
      #pragma unroll
      for (int j = 0; j < 16; ++j) acc[j] += kd * vc[ss * 64 + e0 + j];
    }
    __syncthreads();
  }
  float* dst = part + ((size_t)bh * SPLIT_ + blockIdx.y) * KVSZ_;
  #pragma unroll
  for (int j = 0; j < 16; ++j) dst[d * 64 + e0 + j] = acc[j];
  if ((t & 3) == 0) dst[4096 + d] = ksum;
}

__global__ __launch_bounds__(256) void kv_finalize(
    const float* __restrict__ part, float* __restrict__ fin)
{
  const int bh = blockIdx.x;
  for (int idx = threadIdx.x; idx < KVSZ_; idx += 256) {
    float s = 0.0f;
    for (int p = 0; p < SPLIT_; ++p) s += part[((size_t)bh * SPLIT_ + p) * KVSZ_ + idx];
    if (idx >= 4096) s += EPS_;   // K.sum + EPS (per-component)
    fin[(size_t)bh * KVSZ_ + idx] = s;
  }
}

// ---------------------------------------------------------------------------
// attn[b,s,h,:] = (qf @ KV[b,h]) / (qf . (ksum+eps)) with FUSED q-conv+elu:
// qf = elu(conv(q_proj)) + 1 computed in-register from raw q_proj rows
// s, s-1, s-2 (conv weights broadcast from LDS).
// ---------------------------------------------------------------------------
__global__ __launch_bounds__(256) void attn_out(
    const unsigned short* __restrict__ qp,
    const float* __restrict__ qcw, const float* __restrict__ qcb,
    const float* __restrict__ fin,
    unsigned short* __restrict__ attn)
{
  __shared__ float kv[64 * 64];
  __shared__ float ks[64];
  __shared__ float qw[192];
  __shared__ float qb[64];
  const int t = threadIdx.x;
  const int bh = blockIdx.x, b = bh >> 3, h = bh & 7;
  const int s = blockIdx.y * 64 + (t >> 2);
  const int e0 = (t & 3) << 4;

  const float* src = fin + (size_t)bh * KVSZ_;
  for (int i = t; i < 4096; i += 256) kv[i] = src[i];
  if (t < 64) ks[t] = src[4096 + t];
  if (t < 192) qw[t] = qcw[t];
  if (t < 64) qb[t] = qcb[t];
  __syncthreads();

  const unsigned short* qrow = qp + ((size_t)(b * S_ + s)) * D_ + h * 64;
  float q[64];
  #pragma unroll
  for (int i8 = 0; i8 < 8; ++i8) {
    bf16x8 a0 = *(const bf16x8*)(qrow + i8 * 8);
    bf16x8 a1 = {}, a2 = {};
    if (s >= 1) a1 = *(const bf16x8*)(qrow - D_ + i8 * 8);
    if (s >= 2) a2 = *(const bf16x8*)(qrow - 2 * (size_t)D_ + i8 * 8);
    #pragma unroll
    for (int k = 0; k < 8; ++k) {
      const int c = i8 * 8 + k;
      float v = qw[c * 3 + 2] * b2f((unsigned short)a0[k])
              + qw[c * 3 + 1] * b2f((unsigned short)a1[k])
              + qw[c * 3 + 0] * b2f((unsigned short)a2[k]) + qb[c];
      q[c] = elu1(v);
    }
  }
  float zden = 0.0f;
  #pragma unroll
  for (int dd = 0; dd < 64; ++dd) zden += q[dd] * ks[dd];
  const float z = 1.0f / zden;

  float acc[16] = {};
  for (int dd = 0; dd < 64; ++dd) {
    const float qd = q[dd];
    #pragma unroll
    for (int j = 0; j < 16; ++j) acc[j] += qd * kv[dd * 64 + e0 + j];
  }
  unsigned short* orow = attn + ((size_t)(b * S_ + s)) * D_ + h * 64 + e0;
  bf16x8 o0, o1;
  #pragma unroll
  for (int j = 0; j < 8; ++j) { o0[j] = (short)f2b(acc[j] * z); o1[j] = (short)f2b(acc[8 + j] * z); }
  *(bf16x8*)(orow) = o0;
  *(bf16x8*)(orow + 8) = o1;
}

// ---------------------------------------------------------------------------
// out = LayerNorm(xa + xb) * g + b ; one wave per 512-elem row, fp32 math.
// AF32: xa is fp32 (else bf16).  OF32: out is fp32 (else bf16). xb is bf16.
// ---------------------------------------------------------------------------
template<bool AF32, bool OF32>
__global__ __launch_bounds__(256) void ln_add(
    const void* __restrict__ xa_,
    const unsigned short* __restrict__ xb,
    const float* __restrict__ gg,
    const float* __restrict__ bb,
    void* __restrict__ out_)
{
  const int t = threadIdx.x, lane = t & 63, w = t >> 6;
  const size_t row = (size_t)blockIdx.x * 4 + w;
  const size_t base = row * D_ + lane * 8;

  float v[8];
  if (AF32) {
    const float* xa = (const float*)xa_;
    f32x4 a0 = *(const f32x4*)(xa + base);
    f32x4 a1 = *(const f32x4*)(xa + base + 4);
    #pragma unroll
    for (int i = 0; i < 4; ++i) { v[i] = a0[i]; v[i + 4] = a1[i]; }
  } else {
    bf16x8 a = *(const bf16x8*)((const unsigned short*)xa_ + base);
    #pragma unroll
    for (int i = 0; i < 8; ++i) v[i] = b2f((unsigned short)a[i]);
  }
  bf16x8 c = *(const bf16x8*)(xb + base);
  float sum = 0.0f;
  #pragma unroll
  for (int i = 0; i < 8; ++i) { v[i] += b2f((unsigned short)c[i]); sum += v[i]; }
  #pragma unroll
  for (int off = 1; off < 64; off <<= 1) sum += __shfl_xor(sum, off, 64);
  const float mean = sum * (1.0f / 512.0f);
  float sq = 0.0f;
  #pragma unroll
  for (int i = 0; i < 8; ++i) { const float dd = v[i] - mean; sq += dd * dd; }
  #pragma unroll
  for (int off = 1; off < 64; off <<= 1) sq += __shfl_xor(sq, off, 64);
  const float rstd = rsqrtf(sq * (1.0f / 512.0f) + LN_EPS_);

  if (OF32) {
    float* out = (float*)out_;
    f32x4 o0, o1;
    #pragma unroll
    for (int i = 0; i < 4; ++i) {
      o0[i] = (v[i] - mean) * rstd * gg[lane * 8 + i] + bb[lane * 8 + i];
      o1[i] = (v[i + 4] - mean) * rstd * gg[lane * 8 + i + 4] + bb[lane * 8 + i + 4];
    }
    *(f32x4*)(out + base) = o0;
    *(f32x4*)(out + base + 4) = o1;
  } else {
    unsigned short* out = (unsigned short*)out_;
    bf16x8 o;
    #pragma unroll
    for (int i = 0; i < 8; ++i)
      o[i] = (short)f2b((v[i] - mean) * rstd * gg[lane * 8 + i] + bb[lane * 8 + i]);
    *(bf16x8*)(out + base) = o;
  }
}

// ---------------------------------------------------------------------------
extern "C" void kernel_launch(void* const* d_in, const int* in_sizes, int n_in,
                              void* d_out, int out_size, void* d_ws, size_t ws_size,
                              hipStream_t stream) {
  const float* x    = (const float*)d_in[0];
  const float* wq   = (const float*)d_in[1];
  const float* bq   = (const float*)d_in[2];
  const float* wk   = (const float*)d_in[3];
  const float* bk   = (const float*)d_in[4];
  const float* wv   = (const float*)d_in[5];
  const float* bv   = (const float*)d_in[6];
  const float* wo   = (const float*)d_in[7];
  const float* bo   = (const float*)d_in[8];
  const float* qcw  = (const float*)d_in[9];
  const float* qcb  = (const float*)d_in[10];
  const float* kcw  = (const float*)d_in[11];
  const float* kcb  = (const float*)d_in[12];
  const float* vcw  = (const float*)d_in[13];
  const float* vcb  = (const float*)d_in[14];
  const float* w1   = (const float*)d_in[15];
  const float* b1   = (const float*)d_in[16];
  const float* w2   = (const float*)d_in[17];
  const float* b2   = (const float*)d_in[18];
  const float* ln1g = (const float*)d_in[19];
  const float* ln1b = (const float*)d_in[20];
  const float* ln2g = (const float*)d_in[21];
  const float* ln2b = (const float*)d_in[22];

  const size_t E = (size_t)B_ * S_ * D_;   // 16,777,216 elems per slot
  unsigned short* s0 = (unsigned short*)d_ws;
  unsigned short* s1 = s0 + E;
  unsigned short* s2 = s0 + 2 * E;
  unsigned short* s3 = s0 + 3 * E;
  // part/fin live in s3 AFTER x_bf16 (s3) is dead (post-QKV gemm)
  float* part = (float*)s3;
  float* fin  = part + (size_t)64 * SPLIT_ * KVSZ_;

  // bf16 weights stashed in d_out (dead until the final LN overwrites it)
  unsigned short* wb = (unsigned short*)d_out;
  unsigned short* wqkv_b = wb;               // [1536][512]
  unsigned short* wo_b   = wb + 786432;
  unsigned short* w1_b   = wb + 1048576;
  unsigned short* w2_b   = wb + 1572864;
  float* bqkv = (float*)(wb + 2097152);      // 1536 floats

  const int M = B_ * S_;                     // 32768

  // converts: x -> s3 (bf16), all weights+bias pack in ONE kernel
  cvt_f32_bf16<<<(int)(E / 8 / 256), 256, 0, stream>>>(x, s3, (int)(E / 8));
  cvt_weights<<<1024, 256, 0, stream>>>(wq, wk, wv, wo, w1, w2, bq, bk, bv, wb, bqkv);

  // fused q,k,v projection (RAW, pre-conv): -> s0(q), s1(k), s2(v)
  gemm_bt<2><<<1536, 256, 0, stream>>>(s3, wqkv_b, bqkv, s0, M, 1536, D_, 6);
  // KV / ksum reduction with fused k/v conv (x_bf16 in s3 now dead -> part)
  kv_partial<<<dim3(B_ * H_, SPLIT_), 256, 0, stream>>>(s1, s2, kcw, kcb, vcw, vcb, part);
  kv_finalize<<<B_ * H_, 256, 0, stream>>>(part, fin);
  // attention output with fused q conv+elu: attn -> s1 (k_proj dead)
  attn_out<<<dim3(B_ * H_, S_ / 64), 256, 0, stream>>>(s0, qcw, qcb, fin, s1);
  // output projection: o -> s2 (v_proj dead)
  gemm_bt<0><<<512, 256, 0, stream>>>(s1, wo_b, bo, s2, M, D_, D_, 2);
  // x1 = LN(x + o) -> s3 (part/fin dead)
  ln_add<true, false><<<M / 4, 256, 0, stream>>>(x, s2, ln1g, ln1b, s3);
  // FFN: h (gelu^2) -> s0..s1 (dead); ffn -> s2
  gemm_bt<1><<<1024, 256, 0, stream>>>(s3, w1_b, b1, s0, M, DFF_, D_, 4);
  gemm_bt<0><<<512, 256, 0, stream>>>(s0, w2_b, b2, s2, M, D_, DFF_, 2);
  // out = LN(x1 + ffn) -> fp32 d_out (weight scratch overwritten, now dead)
  ln_add<false, true><<<M / 4, 256, 0, stream>>>(s3, s2, ln2g, ln2b, d_out);
}

// Round 9
// 532.692 us; speedup vs baseline: 1.3805x; 1.1834x over previous
//
#include <hip/hip_runtime.h>
#include <hip/hip_bf16.h>
#include <math.h>

#define B_ 8
#define S_ 4096
#define D_ 512
#define H_ 8
#define DK_ 64
#define DFF_ 1024
#define SPLIT_ 16
#define KVSZ_ 4160   /* 64*64 + 64 (KV matrix + ksum) */
#define EPS_ 1e-6f
#define LN_EPS_ 1e-5f

typedef __attribute__((ext_vector_type(8))) short bf16x8;
typedef __attribute__((ext_vector_type(4))) float f32x4;

static __device__ __forceinline__ float b2f(unsigned short u) {
  unsigned int x = ((unsigned int)u) << 16;
  return __builtin_bit_cast(float, x);
}
static __device__ __forceinline__ unsigned short f2b(float f) {
  unsigned int u = __builtin_bit_cast(unsigned int, f);
  u += 0x7FFFu + ((u >> 16) & 1u);   // round-to-nearest-even
  return (unsigned short)(u >> 16);
}
static __device__ __forceinline__ float elu1(float v) {
  return (v > 0.0f) ? (v + 1.0f) : expf(v);
}

// ---------------------------------------------------------------------------
// fp32 -> bf16 convert (RNE), 8 elems/thread. n8 = n/8.
// ---------------------------------------------------------------------------
__global__ __launch_bounds__(256) void cvt_f32_bf16(
    const float* __restrict__ in, unsigned short* __restrict__ out, int n8)
{
  const int i = blockIdx.x * 256 + threadIdx.x;
  if (i >= n8) return;
  f32x4 a = ((const f32x4*)in)[i * 2];
  f32x4 b = ((const f32x4*)in)[i * 2 + 1];
  bf16x8 o;
  #pragma unroll
  for (int e = 0; e < 4; ++e) { o[e] = (short)f2b(a[e]); o[e + 4] = (short)f2b(b[e]); }
  ((bf16x8*)out)[i] = o;
}

// ---------------------------------------------------------------------------
// All 6 weight matrices -> bf16, packed contiguously at wb. Also packs qkv
// biases into bqkv[1536]. Total vec8 groups = 262144 -> 1024 blocks.
// ---------------------------------------------------------------------------
__global__ __launch_bounds__(256) void cvt_weights(
    const float* __restrict__ wq, const float* __restrict__ wk,
    const float* __restrict__ wv, const float* __restrict__ wo,
    const float* __restrict__ w1, const float* __restrict__ w2,
    const float* __restrict__ bq, const float* __restrict__ bk,
    const float* __restrict__ bv,
    unsigned short* __restrict__ wb, float* __restrict__ bqkv)
{
  const int i = blockIdx.x * 256 + threadIdx.x;   // vec8 id, 262144 total
  const float* src; int rel;
  if (i < 65536)       { src = (i < 32768)  ? wq : wk; rel = i & 32767; }
  else if (i < 131072) { src = (i < 98304)  ? wv : wo; rel = (i - 65536) & 32767; }
  else                 { src = (i < 196608) ? w1 : w2; rel = (i - 131072) & 65535; }
  f32x4 a = ((const f32x4*)src)[rel * 2];
  f32x4 b = ((const f32x4*)src)[rel * 2 + 1];
  bf16x8 o;
  #pragma unroll
  for (int e = 0; e < 4; ++e) { o[e] = (short)f2b(a[e]); o[e + 4] = (short)f2b(b[e]); }
  ((bf16x8*)wb)[i] = o;
  if (i < 1536) bqkv[i] = (i < 512) ? bq[i] : (i < 1024 ? bk[i - 512] : bv[i - 1024]);
}

// ---------------------------------------------------------------------------
// GEMM: C[M,N] = A[M,K] @ W[N,K]^T + bias, bf16 A/W, fp32 bias, bf16 out.
// 128x256 tile, BK=32, 4 waves (each 64x128 = 4x8 16x16 frags).
// 3-deep pipeline, late counted vmcnt. 1-D grid + bijective XCD swizzle.
// EPI: 0 = bias; 1 = bias + gelu(x)^2 (exact erf); 2 = fused-QKV dst routing.
// ---------------------------------------------------------------------------
template<int EPI>
__global__ __launch_bounds__(256, 2) void gemm_bt(
    const unsigned short* __restrict__ A,
    const unsigned short* __restrict__ W,
    const float* __restrict__ bias,
    unsigned short* __restrict__ C,
    int M, int N, int K, int ntx)
{
  __shared__ unsigned short sA[3 * 128 * 32];   // 24 KB
  __shared__ unsigned short sB[3 * 256 * 32];   // 48 KB
  const int t = threadIdx.x;
  const int wave = t >> 6;
  const int lane = t & 63;
  const int bid = blockIdx.x;
  const int logical = (bid & 7) * ((int)gridDim.x >> 3) + (bid >> 3);
  const int row0 = (logical / ntx) << 7;   // 128-row tile
  const int col0 = (logical % ntx) << 8;   // 256-col tile

  f32x4 acc[4][8] = {};

  const int srow = (wave << 4) + (lane >> 2);   // 0..63
  const int scol = (lane & 3) << 3;             // 0,8,16,24
  const unsigned short* ga = A + (size_t)(row0 + srow) * K + scol;
  const unsigned short* gb = W + (size_t)(col0 + srow) * K + scol;
  const int ldsoff = (wave << 9);               // wave-uniform elem offset

  const int wm = (wave >> 1) << 6;    // wave A-row quadrant (0/64)
  const int wn = (wave & 1) << 7;     // wave C-col half (0/128)
  const int fr = lane & 15;           // fragment row (A-M / B-N) index
  const int fk = (lane >> 4) << 3;    // fragment K offset (8 contiguous)

  #define STAGE(bufsel, kt)                                                     \
    {                                                                           \
      _Pragma("unroll")                                                         \
      for (int i = 0; i < 2; ++i)                                               \
        __builtin_amdgcn_global_load_lds(                                       \
            (const __attribute__((address_space(1))) void*)(ga + (size_t)(i * 64) * K + (kt)), \
            (__attribute__((address_space(3))) void*)(sA + (bufsel) * 4096 + i * 2048 + ldsoff), \
            16, 0, 0);                                                          \
      _Pragma("unroll")                                                         \
      for (int i = 0; i < 4; ++i)                                               \
        __builtin_amdgcn_global_load_lds(                                       \
            (const __attribute__((address_space(1))) void*)(gb + (size_t)(i * 64) * K + (kt)), \
            (__attribute__((address_space(3))) void*)(sB + (bufsel) * 8192 + i * 2048 + ldsoff), \
            16, 0, 0);                                                          \
    }

  const int nt = K >> 5;
  STAGE(0, 0);
  STAGE(1, 32);

  int cur = 0, nxt = 2;
  for (int kt = 0; kt < nt; ++kt) {
    __builtin_amdgcn_s_barrier();
    asm volatile("" ::: "memory");
    if (kt + 2 < nt) {
      STAGE(nxt, (kt + 2) * 32);
      nxt = (nxt == 2) ? 0 : nxt + 1;
      asm volatile("s_waitcnt vmcnt(12)" ::: "memory");
    } else if (kt + 1 < nt) {
      asm volatile("s_waitcnt vmcnt(6)" ::: "memory");
    } else {
      asm volatile("s_waitcnt vmcnt(0)" ::: "memory");
    }

    const unsigned short* pA = sA + cur * 4096;
    const unsigned short* pB = sB + cur * 8192;
    bf16x8 af[4], bfv[8];
    #pragma unroll
    for (int i = 0; i < 4; ++i)
      af[i] = *(const bf16x8*)(pA + (wm + i * 16 + fr) * 32 + fk);
    #pragma unroll
    for (int j = 0; j < 8; ++j)
      bfv[j] = *(const bf16x8*)(pB + (wn + j * 16 + fr) * 32 + fk);
    #pragma unroll
    for (int i = 0; i < 4; ++i)
      #pragma unroll
      for (int j = 0; j < 8; ++j)
        acc[i][j] = __builtin_amdgcn_mfma_f32_16x16x32_bf16(af[i], bfv[j], acc[i][j], 0, 0, 0);

    cur = (cur == 2) ? 0 : cur + 1;
  }
  #undef STAGE

  // C/D layout (m89-verified): col = lane&15, row = (lane>>4)*4 + reg
  const int crow0 = row0 + wm + ((lane >> 4) << 2);
  const int ccol0 = col0 + wn + fr;
  unsigned short* Cb = C;
  if (EPI == 2) Cb = C + (size_t)(col0 >> 9) * M * 512;   // q/k/v slot
  const int cstride = (EPI == 2) ? 512 : N;
  #pragma unroll
  for (int j = 0; j < 8; ++j) {
    const int col = ccol0 + j * 16;
    const float bv = bias[col];
    const int lcol = (EPI == 2) ? (col & 511) : col;
    #pragma unroll
    for (int i = 0; i < 4; ++i) {
      #pragma unroll
      for (int r = 0; r < 4; ++r) {
        float v = acc[i][j][r] + bv;
        if (EPI == 1) {
          float g = 0.5f * v * (1.0f + erff(v * 0.70710678118654752f));
          v = g * g;
        }
        Cb[(size_t)(crow0 + i * 16 + r) * cstride + lcol] = f2b(v);
      }
    }
  }
}

// ---------------------------------------------------------------------------
// q depthwise causal conv + elu+1, AND fused Z denominator:
// z[bs*8+h] = 1 / sum_d qf[bs,h,d]*(ksum[h,d]+eps)   (8-lane shfl reduce).
// One thread per 8 channels; 8 consecutive lanes cover one (bs, head).
// ---------------------------------------------------------------------------
__global__ __launch_bounds__(256) void dwconv_q(
    const unsigned short* __restrict__ in,
    const float* __restrict__ cw,
    const float* __restrict__ cb,
    const float* __restrict__ fin,      // per bh: KV[4096] + ksum[64] (+eps)
    float* __restrict__ zout,
    unsigned short* __restrict__ out)
{
  const int vid = blockIdx.x * 256 + threadIdx.x; // vec8 index, B*S*64 total
  const int d8 = vid & 63;
  const int bs = vid >> 6;        // b*S + s
  const int s  = bs & (S_ - 1);
  const int d0 = d8 << 3;
  const int dk0 = d0 & 63;        // channel within head_dim
  const int h  = d8 >> 3;
  const int bh = (bs >> 12) * 8 + h;

  float acc[8], wf[3][8];
  #pragma unroll
  for (int i = 0; i < 8; ++i) acc[i] = cb[dk0 + i];
  #pragma unroll
  for (int j = 0; j < 3; ++j)
    #pragma unroll
    for (int i = 0; i < 8; ++i) wf[j][i] = cw[(dk0 + i) * 3 + j];

  const size_t base = (size_t)bs * D_ + d0;
  #pragma unroll
  for (int j = 0; j < 3; ++j) {
    const int sr = s - 2 + j;
    if (sr >= 0) {
      bf16x8 xv = *(const bf16x8*)(in + base - (size_t)(2 - j) * D_);
      #pragma unroll
      for (int i = 0; i < 8; ++i) acc[i] += wf[j][i] * b2f((unsigned short)xv[i]);
    }
  }
  const float* ksumf = fin + (size_t)bh * KVSZ_ + 4096 + dk0;
  float part = 0.0f;
  bf16x8 ov;
  #pragma unroll
  for (int i = 0; i < 8; ++i) {
    const float v = elu1(acc[i]);
    part += v * ksumf[i];
    ov[i] = (short)f2b(v);
  }
  *(bf16x8*)(out + base) = ov;
  part += __shfl_xor(part, 1, 64);
  part += __shfl_xor(part, 2, 64);
  part += __shfl_xor(part, 4, 64);
  if ((threadIdx.x & 7) == 0) zout[bs * 8 + h] = 1.0f / part;
}

// ---------------------------------------------------------------------------
// KV partial reduction with FUSED depthwise conv (+elu+1 for k).
// ---------------------------------------------------------------------------
__global__ __launch_bounds__(256) void kv_partial(
    const unsigned short* __restrict__ kp,
    const unsigned short* __restrict__ vp,
    const float* __restrict__ kcw, const float* __restrict__ kcb,
    const float* __restrict__ vcw, const float* __restrict__ vcb,
    float* __restrict__ part)
{
  __shared__ float kc[16 * 64];
  __shared__ float vc[16 * 64];
  const int t = threadIdx.x;
  const int bh = blockIdx.x;
  const int b = bh >> 3, h = bh & 7;
  const int s0 = blockIdx.y * (S_ / SPLIT_);
  const int d = t >> 2;
  const int e0 = (t & 3) << 4;
  const int lr = (t & 127) >> 3;   // 0..15 row in chunk
  const int lc = (t & 7) << 3;     // 0..56 col
  const bool isv = t >= 128;

  const float* cw = isv ? vcw : kcw;
  const float* cb = isv ? vcb : kcb;
  float w0[8], w1[8], w2[8], wb[8];
  #pragma unroll
  for (int i = 0; i < 8; ++i) {
    w0[i] = cw[(lc + i) * 3 + 0];
    w1[i] = cw[(lc + i) * 3 + 1];
    w2[i] = cw[(lc + i) * 3 + 2];
    wb[i] = cb[lc + i];
  }
  const unsigned short* src = isv ? vp : kp;
  float* dstc = isv ? vc : kc;

  float acc[16] = {};
  float ksum = 0.0f;

  for (int chunk = 0; chunk < S_ / SPLIT_; chunk += 16) {
    const int s = s0 + chunk + lr;
    const size_t g = ((size_t)(b * S_ + s)) * D_ + h * 64 + lc;
    bf16x8 r0 = *(const bf16x8*)(src + g);
    bf16x8 r1 = {}, r2 = {};
    if (s >= 1) r1 = *(const bf16x8*)(src + g - D_);
    if (s >= 2) r2 = *(const bf16x8*)(src + g - 2 * D_);
    #pragma unroll
    for (int i = 0; i < 8; ++i) {
      float v = w2[i] * b2f((unsigned short)r0[i])
              + w1[i] * b2f((unsigned short)r1[i])
              + w0[i] * b2f((unsigned short)r2[i]) + wb[i];
      if (!isv) v = elu1(v);
      dstc[lr * 64 + lc + i] = v;
    }
    __syncthreads();
    #pragma unroll 4
    for (int ss = 0; ss < 16; ++ss) {
      const float kd = kc[ss * 64 + d];
      ksum += kd;
      #pragma unroll
      for (int j = 0; j < 16; ++j) acc[j] += kd * vc[ss * 64 + e0 + j];
    }
    __syncthreads();
  }
  float* dst = part + ((size_t)bh * SPLIT_ + blockIdx.y) * KVSZ_;
  #pragma unroll
  for (int j = 0; j < 16; ++j) dst[d * 64 + e0 + j] = acc[j];
  if ((t & 3) == 0) dst[4096 + d] = ksum;
}

__global__ __launch_bounds__(256) void kv_finalize(
    const float* __restrict__ part, float* __restrict__ fin)
{
  const int bh = blockIdx.x;
  for (int idx = threadIdx.x; idx < KVSZ_; idx += 256) {
    float s = 0.0f;
    for (int p = 0; p < SPLIT_; ++p) s += part[((size_t)bh * SPLIT_ + p) * KVSZ_ + idx];
    if (idx >= 4096) s += EPS_;   // K.sum + EPS (per-component)
    fin[(size_t)bh * KVSZ_ + idx] = s;
  }
}

// ---------------------------------------------------------------------------
// attn via MFMA: per (128-row tile, head) block, attn[m, h*64+e] =
// z[m,h] * sum_d qf[m,h*64+d] * KV[d][e].  B-operand = KV^T bf16 in LDS
// ([64][72] pad: row stride 144B -> only 2-way bank aliasing, free).
// A-fragments loaded straight from global (16 lanes x 4 k-chunks fill
// contiguous 64B per row -> coalesced, single-use data).
// ---------------------------------------------------------------------------
__global__ __launch_bounds__(256) void attn_mm(
    const unsigned short* __restrict__ qf,
    const float* __restrict__ fin,
    const float* __restrict__ z,
    unsigned short* __restrict__ attn)
{
  __shared__ unsigned short kvT[64 * 72];
  const int t = threadIdx.x;
  const int wave = t >> 6, lane = t & 63;
  const int h = (int)blockIdx.x & 7;
  const int m0 = ((int)blockIdx.x >> 3) << 7;
  const int bh = (m0 >> 12) * 8 + h;

  const float* kvsrc = fin + (size_t)bh * KVSZ_;
  for (int i = t; i < 4096; i += 256) {
    const int d = i >> 6, e = i & 63;
    kvT[e * 72 + d] = f2b(kvsrc[i]);
  }
  __syncthreads();

  const int fr = lane & 15;
  const int fk = (lane >> 4) << 3;   // 0,8,16,24
  const int row_w = m0 + wave * 32;

  bf16x8 bfv[4][2];
  #pragma unroll
  for (int j = 0; j < 4; ++j)
    #pragma unroll
    for (int ks = 0; ks < 2; ++ks)
      bfv[j][ks] = *(const bf16x8*)(kvT + (j * 16 + fr) * 72 + ks * 32 + fk);

  f32x4 acc[2][4] = {};
  #pragma unroll
  for (int i = 0; i < 2; ++i) {
    #pragma unroll
    for (int ks = 0; ks < 2; ++ks) {
      bf16x8 af = *(const bf16x8*)(qf +
          (size_t)(row_w + i * 16 + fr) * D_ + h * 64 + ks * 32 + fk);
      #pragma unroll
      for (int j = 0; j < 4; ++j)
        acc[i][j] = __builtin_amdgcn_mfma_f32_16x16x32_bf16(af, bfv[j][ks], acc[i][j], 0, 0, 0);
    }
  }

  // C/D layout: col = lane&15, row = (lane>>4)*4 + reg
  #pragma unroll
  for (int i = 0; i < 2; ++i) {
    #pragma unroll
    for (int r = 0; r < 4; ++r) {
      const int row = row_w + i * 16 + ((lane >> 4) << 2) + r;
      const float zz = z[row * 8 + h];
      unsigned short* orow = attn + (size_t)row * D_ + h * 64 + fr;
      #pragma unroll
      for (int j = 0; j < 4; ++j)
        orow[j * 16] = f2b(acc[i][j][r] * zz);
    }
  }
}

// ---------------------------------------------------------------------------
// out = LayerNorm(xa + xb) * g + b ; one wave per 512-elem row, fp32 math.
// ---------------------------------------------------------------------------
template<bool AF32, bool OF32>
__global__ __launch_bounds__(256) void ln_add(
    const void* __restrict__ xa_,
    const unsigned short* __restrict__ xb,
    const float* __restrict__ gg,
    const float* __restrict__ bb,
    void* __restrict__ out_)
{
  const int t = threadIdx.x, lane = t & 63, w = t >> 6;
  const size_t row = (size_t)blockIdx.x * 4 + w;
  const size_t base = row * D_ + lane * 8;

  float v[8];
  if (AF32) {
    const float* xa = (const float*)xa_;
    f32x4 a0 = *(const f32x4*)(xa + base);
    f32x4 a1 = *(const f32x4*)(xa + base + 4);
    #pragma unroll
    for (int i = 0; i < 4; ++i) { v[i] = a0[i]; v[i + 4] = a1[i]; }
  } else {
    bf16x8 a = *(const bf16x8*)((const unsigned short*)xa_ + base);
    #pragma unroll
    for (int i = 0; i < 8; ++i) v[i] = b2f((unsigned short)a[i]);
  }
  bf16x8 c = *(const bf16x8*)(xb + base);
  float sum = 0.0f;
  #pragma unroll
  for (int i = 0; i < 8; ++i) { v[i] += b2f((unsigned short)c[i]); sum += v[i]; }
  #pragma unroll
  for (int off = 1; off < 64; off <<= 1) sum += __shfl_xor(sum, off, 64);
  const float mean = sum * (1.0f / 512.0f);
  float sq = 0.0f;
  #pragma unroll
  for (int i = 0; i < 8; ++i) { const float dd = v[i] - mean; sq += dd * dd; }
  #pragma unroll
  for (int off = 1; off < 64; off <<= 1) sq += __shfl_xor(sq, off, 64);
  const float rstd = rsqrtf(sq * (1.0f / 512.0f) + LN_EPS_);

  if (OF32) {
    float* out = (float*)out_;
    f32x4 o0, o1;
    #pragma unroll
    for (int i = 0; i < 4; ++i) {
      o0[i] = (v[i] - mean) * rstd * gg[lane * 8 + i] + bb[lane * 8 + i];
      o1[i] = (v[i + 4] - mean) * rstd * gg[lane * 8 + i + 4] + bb[lane * 8 + i + 4];
    }
    *(f32x4*)(out + base) = o0;
    *(f32x4*)(out + base + 4) = o1;
  } else {
    unsigned short* out = (unsigned short*)out_;
    bf16x8 o;
    #pragma unroll
    for (int i = 0; i < 8; ++i)
      o[i] = (short)f2b((v[i] - mean) * rstd * gg[lane * 8 + i] + bb[lane * 8 + i]);
    *(bf16x8*)(out + base) = o;
  }
}

// ---------------------------------------------------------------------------
extern "C" void kernel_launch(void* const* d_in, const int* in_sizes, int n_in,
                              void* d_out, int out_size, void* d_ws, size_t ws_size,
                              hipStream_t stream) {
  const float* x    = (const float*)d_in[0];
  const float* wq   = (const float*)d_in[1];
  const float* bq   = (const float*)d_in[2];
  const float* wk   = (const float*)d_in[3];
  const float* bk   = (const float*)d_in[4];
  const float* wv   = (const float*)d_in[5];
  const float* bv   = (const float*)d_in[6];
  const float* wo   = (const float*)d_in[7];
  const float* bo   = (const float*)d_in[8];
  const float* qcw  = (const float*)d_in[9];
  const float* qcb  = (const float*)d_in[10];
  const float* kcw  = (const float*)d_in[11];
  const float* kcb  = (const float*)d_in[12];
  const float* vcw  = (const float*)d_in[13];
  const float* vcb  = (const float*)d_in[14];
  const float* w1   = (const float*)d_in[15];
  const float* b1   = (const float*)d_in[16];
  const float* w2   = (const float*)d_in[17];
  const float* b2   = (const float*)d_in[18];
  const float* ln1g = (const float*)d_in[19];
  const float* ln1b = (const float*)d_in[20];
  const float* ln2g = (const float*)d_in[21];
  const float* ln2b = (const float*)d_in[22];

  const size_t E = (size_t)B_ * S_ * D_;   // 16,777,216 elems per slot
  unsigned short* s0 = (unsigned short*)d_ws;
  unsigned short* s1 = s0 + E;
  unsigned short* s2 = s0 + 2 * E;
  unsigned short* s3 = s0 + 3 * E;
  // s3 after x_bf16 dies: part (17MB) | fin (1.06MB) | z (1MB)
  float* part = (float*)s3;
  float* fin  = part + (size_t)64 * SPLIT_ * KVSZ_;
  float* zbuf = fin + (size_t)64 * KVSZ_;

  unsigned short* wb = (unsigned short*)d_out;
  unsigned short* wqkv_b = wb;               // [1536][512]
  unsigned short* wo_b   = wb + 786432;
  unsigned short* w1_b   = wb + 1048576;
  unsigned short* w2_b   = wb + 1572864;
  float* bqkv = (float*)(wb + 2097152);      // 1536 floats

  const int M = B_ * S_;                     // 32768

  cvt_f32_bf16<<<(int)(E / 8 / 256), 256, 0, stream>>>(x, s3, (int)(E / 8));
  cvt_weights<<<1024, 256, 0, stream>>>(wq, wk, wv, wo, w1, w2, bq, bk, bv, wb, bqkv);

  // fused q,k,v projection (RAW, pre-conv): -> s0(q), s1(k), s2(v)
  gemm_bt<2><<<1536, 256, 0, stream>>>(s3, wqkv_b, bqkv, s0, M, 1536, D_, 6);
  // KV / ksum with fused k/v conv (x_bf16 dead -> part in s3)
  kv_partial<<<dim3(B_ * H_, SPLIT_), 256, 0, stream>>>(s1, s2, kcw, kcb, vcw, vcb, part);
  kv_finalize<<<B_ * H_, 256, 0, stream>>>(part, fin);
  // q conv + elu+1 + Z denominators: qf -> s1 (k_raw dead), z -> zbuf
  dwconv_q<<<M * 64 / 256, 256, 0, stream>>>(s0, qcw, qcb, fin, zbuf, s1);
  // attention matvec on MFMA: attn -> s0 (q_raw dead)
  attn_mm<<<(M / 128) * H_, 256, 0, stream>>>(s1, fin, zbuf, s0);
  // output projection: o -> s2 (v_raw dead)
  gemm_bt<0><<<512, 256, 0, stream>>>(s0, wo_b, bo, s2, M, D_, D_, 2);
  // x1 = LN(x + o) -> s3 (part/fin/z dead)
  ln_add<true, false><<<M / 4, 256, 0, stream>>>(x, s2, ln1g, ln1b, s3);
  // FFN: h (gelu^2) -> s0..s1; ffn -> s2
  gemm_bt<1><<<1024, 256, 0, stream>>>(s3, w1_b, b1, s0, M, DFF_, D_, 4);
  gemm_bt<0><<<512, 256, 0, stream>>>(s0, w2_b, b2, s2, M, D_, DFF_, 2);
  // out = LN(x1 + ffn) -> fp32 d_out
  ln_add<false, true><<<M / 4, 256, 0, stream>>>(s3, s2, ln2g, ln2b, d_out);
}